// Round 1
// baseline (354.747 us; speedup 1.0000x reference)
//
#include <hip/hip_runtime.h>
#include <math.h>

#define H 32
#define BSEG 16
#define NPB 16   // nodes per chunk (512 threads / 32 lanes)

// ---------------- init: h = relu(x@proj_w + proj_b); G[n,k,o]; agg = 0 ----------------
__global__ __launch_bounds__(512) void k_init(
    const float* __restrict__ x, const float* __restrict__ proj_w, const float* __restrict__ proj_b,
    const float* __restrict__ e2w, const float* __restrict__ e2b,
    float* __restrict__ h, float* __restrict__ G, float* __restrict__ agg,
    int N, int nodes_per_block)
{
    __shared__ float w2s[8 * 1024];
    __shared__ float b2s[1024];
    __shared__ float hs[NPB][H];
    for (int i = threadIdx.x; i < 8192; i += 512) w2s[i] = e2w[i];
    for (int i = threadIdx.x; i < 1024; i += 512) b2s[i] = e2b[i];
    __syncthreads();

    int ln = threadIdx.x >> 5;
    int o  = threadIdx.x & 31;
    int base = blockIdx.x * nodes_per_block;
    int endn = min(base + nodes_per_block, N);
    for (int n0 = base; n0 < endn; n0 += NPB) {
        int n = n0 + ln;
        bool valid = (n < endn);
        float hv = 0.f;
        if (valid) {
            float acc = proj_b[o];
            #pragma unroll
            for (int i = 0; i < 4; ++i) acc += x[n * 4 + i] * proj_w[i * H + o];
            hv = fmaxf(acc, 0.f);
            h[n * H + o] = hv;
            agg[n * H + o] = 0.f;
        }
        hs[ln][o] = hv;
        __syncthreads();
        if (valid) {
            float acc[8] = {0.f,0.f,0.f,0.f,0.f,0.f,0.f,0.f};
            float accb = 0.f;
            for (int i = 0; i < H; ++i) {
                float hvi = hs[ln][i];
                #pragma unroll
                for (int k = 0; k < 8; ++k) acc[k] += hvi * w2s[k * 1024 + i * H + o];
                accb += hvi * b2s[i * H + o];
            }
            float* Gp = G + (size_t)n * 288;
            #pragma unroll
            for (int k = 0; k < 8; ++k) Gp[k * H + o] = acc[k];
            Gp[8 * H + o] = accb;
        }
        __syncthreads();
    }
}

// ---------------- edges: m[e,o] = Σ_k t_k G[src,k,o] + G[src,8,o]; atomic agg[dst] ----------------
__global__ __launch_bounds__(256) void k_edge(
    const int* __restrict__ ei, const float* __restrict__ ea,
    const float* __restrict__ e1w, const float* __restrict__ e1b,
    const float* __restrict__ G, float* __restrict__ agg, int E)
{
    int tid = blockIdx.x * 256 + threadIdx.x;
    int e = tid >> 5;
    int o = tid & 31;
    if (e >= E) return;
    int src = ei[e];
    int dst = ei[E + e];
    float a = ea[e];
    const float* Gp = G + (size_t)src * 288;
    float m = Gp[8 * H + o];
    #pragma unroll
    for (int k = 0; k < 8; ++k) {
        float t = fmaxf(a * e1w[k] + e1b[k], 0.f);
        m += t * Gp[k * H + o];
    }
    atomicAdd(&agg[dst * H + o], m);
}

// ---------------- node update: GRU(h, agg) -> h; re-zero agg; optionally recompute G ----------------
__global__ __launch_bounds__(512) void k_update(
    float* __restrict__ h, float* __restrict__ agg,
    const float* __restrict__ root_w, const float* __restrict__ conv_b,
    const float* __restrict__ gru_wi, const float* __restrict__ gru_wh,
    const float* __restrict__ gru_bi, const float* __restrict__ gru_bh,
    const float* __restrict__ e2w, const float* __restrict__ e2b,
    float* __restrict__ G, int N, int nodes_per_block, int computeG)
{
    __shared__ float w2s[8 * 1024];
    __shared__ float b2s[1024];
    __shared__ float rws[H * H];
    __shared__ float wiT[H * 96];
    __shared__ float whT[H * 96];
    __shared__ float hs[NPB][H];
    __shared__ float outs[NPB][H];

    for (int i = threadIdx.x; i < 8192; i += 512) w2s[i] = e2w[i];
    for (int i = threadIdx.x; i < 1024; i += 512) b2s[i] = e2b[i];
    for (int i = threadIdx.x; i < 1024; i += 512) rws[i] = root_w[i];
    for (int i = threadIdx.x; i < 3072; i += 512) {
        int j = i / H, ii = i % H;         // j in [0,96)
        wiT[ii * 96 + j] = gru_wi[j * H + ii];
        whT[ii * 96 + j] = gru_wh[j * H + ii];
    }
    __syncthreads();

    int ln = threadIdx.x >> 5;
    int o  = threadIdx.x & 31;
    int base = blockIdx.x * nodes_per_block;
    int endn = min(base + nodes_per_block, N);
    for (int n0 = base; n0 < endn; n0 += NPB) {
        int n = n0 + ln;
        bool valid = (n < endn);
        float hv = valid ? h[n * H + o] : 0.f;
        hs[ln][o] = hv;
        __syncthreads();
        float outv = 0.f;
        if (valid) {
            float tmp = conv_b[o] + agg[n * H + o];
            agg[n * H + o] = 0.f;          // re-zero for next iteration's atomics
            for (int i = 0; i < H; ++i) tmp += hs[ln][i] * rws[i * H + o];
            outv = fmaxf(tmp, 0.f);
        }
        outs[ln][o] = outv;
        __syncthreads();
        float hnew = 0.f;
        if (valid) {
            float gi0 = gru_bi[o],         gh0 = gru_bh[o];
            float gi1 = gru_bi[H + o],     gh1 = gru_bh[H + o];
            float gi2 = gru_bi[2 * H + o], gh2 = gru_bh[2 * H + o];
            for (int i = 0; i < H; ++i) {
                float ov = outs[ln][i], hvi = hs[ln][i];
                gi0 += ov * wiT[i * 96 + o];
                gi1 += ov * wiT[i * 96 + H + o];
                gi2 += ov * wiT[i * 96 + 2 * H + o];
                gh0 += hvi * whT[i * 96 + o];
                gh1 += hvi * whT[i * 96 + H + o];
                gh2 += hvi * whT[i * 96 + 2 * H + o];
            }
            float r = 1.f / (1.f + expf(-(gi0 + gh0)));
            float z = 1.f / (1.f + expf(-(gi1 + gh1)));
            float nn = tanhf(gi2 + r * gh2);
            hnew = (1.f - z) * nn + z * hv;
            h[n * H + o] = hnew;
        }
        __syncthreads();
        hs[ln][o] = hnew;
        __syncthreads();
        if (computeG && valid) {
            float acc[8] = {0.f,0.f,0.f,0.f,0.f,0.f,0.f,0.f};
            float accb = 0.f;
            for (int i = 0; i < H; ++i) {
                float hvi = hs[ln][i];
                #pragma unroll
                for (int k = 0; k < 8; ++k) acc[k] += hvi * w2s[k * 1024 + i * H + o];
                accb += hvi * b2s[i * H + o];
            }
            float* Gp = G + (size_t)n * 288;
            #pragma unroll
            for (int k = 0; k < 8; ++k) Gp[k * H + o] = acc[k];
            Gp[8 * H + o] = accb;
        }
        __syncthreads();
    }
}

// ---------------- readout: q from LSTM biases; segment softmax(h·q) -> r_out ----------------
__global__ __launch_bounds__(256) void k_readout(
    const float* __restrict__ h, const int* __restrict__ batch,
    const float* __restrict__ lstm_bi, const float* __restrict__ lstm_bh,
    float* __restrict__ q, float* __restrict__ r_out, float* __restrict__ ebuf, int N)
{
    int b = blockIdx.x;
    int tid = threadIdx.x;

    // segment boundaries (batch sorted): lower_bound(b), lower_bound(b+1)
    int lo = 0, hi = N;
    while (lo < hi) { int mid = (lo + hi) >> 1; if (batch[mid] < b) lo = mid + 1; else hi = mid; }
    int s = lo;
    lo = 0; hi = N;
    while (lo < hi) { int mid = (lo + hi) >> 1; if (batch[mid] < b + 1) lo = mid + 1; else hi = mid; }
    int epos = lo;

    __shared__ float qs[H];
    if (tid < H) {
        float g0 = lstm_bi[tid] + lstm_bh[tid];
        float g2 = lstm_bi[2 * H + tid] + lstm_bh[2 * H + tid];
        float g3 = lstm_bi[3 * H + tid] + lstm_bh[3 * H + tid];
        float ig = 1.f / (1.f + expf(-g0));
        float gg = tanhf(g2);
        float og = 1.f / (1.f + expf(-g3));
        float qv = og * tanhf(ig * gg);     // cL starts at 0, f_g*0 drops out
        qs[tid] = qv;
        q[b * H + tid] = qv;
    }
    __syncthreads();

    int ln = tid >> 5, o = tid & 31;        // 8 groups x 32 lanes
    float mloc = -INFINITY;
    for (int n = s + ln; n < epos; n += 8) {
        float v = h[n * H + o] * qs[o];
        #pragma unroll
        for (int m = 16; m >= 1; m >>= 1) v += __shfl_xor(v, m);
        if (o == 0) ebuf[n] = v;
        mloc = fmaxf(mloc, v);
    }
    __shared__ float red[256];
    red[tid] = mloc;
    __syncthreads();
    for (int st = 128; st >= 1; st >>= 1) {
        if (tid < st) red[tid] = fmaxf(red[tid], red[tid + st]);
        __syncthreads();
    }
    float emax = red[0];
    __syncthreads();

    float vacc = 0.f, sacc = 0.f;
    for (int n = s + ln; n < epos; n += 8) {
        float a = expf(ebuf[n] - emax);
        vacc += a * h[n * H + o];
        if (o == 0) sacc += a;
    }
    __shared__ float vsh[8][H];
    __shared__ float ssh[8];
    vsh[ln][o] = vacc;
    if (o == 0) ssh[ln] = sacc;
    __syncthreads();
    if (tid < H) {
        float v = 0.f, stot = 0.f;
        for (int g = 0; g < 8; ++g) { v += vsh[g][tid]; stot += ssh[g]; }
        r_out[b * H + tid] = (stot > 0.f) ? v / stot : 0.f;
    }
}

// ---------------- final MLP on (16, 64) ----------------
__global__ __launch_bounds__(512) void k_mlp(
    const float* __restrict__ q, const float* __restrict__ r_out,
    const float* __restrict__ f1w, const float* __restrict__ f1b,
    const float* __restrict__ f2w, const float* __restrict__ f2b,
    const float* __restrict__ f3w, const float* __restrict__ f3b,
    float* __restrict__ out)
{
    __shared__ float qsm[BSEG][2 * H];
    __shared__ float o1[BSEG][H];
    __shared__ float o2[BSEG][H];
    int tid = threadIdx.x;
    int b = tid >> 5, j = tid & 31;
    qsm[b][j] = q[b * H + j];
    qsm[b][H + j] = r_out[b * H + j];
    __syncthreads();
    float acc = f1b[j];
    for (int i = 0; i < 2 * H; ++i) acc += qsm[b][i] * f1w[i * H + j];
    o1[b][j] = fmaxf(acc, 0.f);
    __syncthreads();
    acc = f2b[j];
    for (int i = 0; i < H; ++i) acc += o1[b][i] * f2w[i * H + j];
    o2[b][j] = fmaxf(acc, 0.f);
    __syncthreads();
    float v = o2[b][j] * f3w[j];
    #pragma unroll
    for (int m = 16; m >= 1; m >>= 1) v += __shfl_xor(v, m);
    if (j == 0) out[b] = v + f3b[0];
}

extern "C" void kernel_launch(void* const* d_in, const int* in_sizes, int n_in,
                              void* d_out, int out_size, void* d_ws, size_t ws_size,
                              hipStream_t stream)
{
    const float* x      = (const float*)d_in[0];
    const int*   ei     = (const int*)d_in[1];
    const float* ea     = (const float*)d_in[2];
    const int*   batch  = (const int*)d_in[3];
    const float* proj_w = (const float*)d_in[4];
    const float* proj_b = (const float*)d_in[5];
    const float* e1w    = (const float*)d_in[6];
    const float* e1b    = (const float*)d_in[7];
    const float* e2w    = (const float*)d_in[8];
    const float* e2b    = (const float*)d_in[9];
    const float* root_w = (const float*)d_in[10];
    const float* conv_b = (const float*)d_in[11];
    const float* gru_wi = (const float*)d_in[12];
    const float* gru_wh = (const float*)d_in[13];
    const float* gru_bi = (const float*)d_in[14];
    const float* gru_bh = (const float*)d_in[15];
    const float* lstm_bi = (const float*)d_in[18];
    const float* lstm_bh = (const float*)d_in[19];
    const float* f1w    = (const float*)d_in[20];
    const float* f1b    = (const float*)d_in[21];
    const float* f2w    = (const float*)d_in[22];
    const float* f2b    = (const float*)d_in[23];
    const float* f3w    = (const float*)d_in[24];
    const float* f3b    = (const float*)d_in[25];

    const int N = in_sizes[0] / 4;
    const int E = in_sizes[2];

    float* ws   = (float*)d_ws;
    float* h    = ws;                       // N*H
    float* G    = h + (size_t)N * H;        // N*288
    float* agg  = G + (size_t)N * 288;      // N*H
    float* ebuf = agg + (size_t)N * H;      // N
    float* qbuf = ebuf + N;                 // BSEG*H
    float* rbuf = qbuf + BSEG * H;          // BSEG*H

    const int NPBK = 80;                    // nodes per block
    const int nblocks = (N + NPBK - 1) / NPBK;
    const int eblocks = (E * 32 + 255) / 256;

    k_init<<<nblocks, 512, 0, stream>>>(x, proj_w, proj_b, e2w, e2b, h, G, agg, N, NPBK);
    for (int it = 0; it < 3; ++it) {
        k_edge<<<eblocks, 256, 0, stream>>>(ei, ea, e1w, e1b, G, agg, E);
        k_update<<<nblocks, 512, 0, stream>>>(h, agg, root_w, conv_b, gru_wi, gru_wh,
                                              gru_bi, gru_bh, e2w, e2b, G, N, NPBK, it < 2 ? 1 : 0);
    }
    k_readout<<<BSEG, 256, 0, stream>>>(h, batch, lstm_bi, lstm_bh, qbuf, rbuf, ebuf, N);
    k_mlp<<<1, 512, 0, stream>>>(qbuf, rbuf, f1w, f1b, f2w, f2b, f3w, f3b, (float*)d_out);
}

// Round 2
// 279.722 us; speedup vs baseline: 1.2682x; 1.2682x over previous
//
#include <hip/hip_runtime.h>
#include <math.h>

#define H 32
#define BSEG 16
#define NPB 16     // nodes per chunk (512 threads / 32 lanes)
#define CHUNKS 32  // readout chunks per segment

// ---------------- init: h = relu(x@proj_w + proj_b); G[n,k,o]; agg = 0 ----------------
__global__ __launch_bounds__(512) void k_init(
    const float* __restrict__ x, const float* __restrict__ proj_w, const float* __restrict__ proj_b,
    const float* __restrict__ e2w, const float* __restrict__ e2b,
    float* __restrict__ h, float* __restrict__ G, float* __restrict__ agg,
    int N, int nodes_per_block)
{
    __shared__ float w2s[8 * 1024];
    __shared__ float b2s[1024];
    __shared__ float hs[NPB][H];
    for (int i = threadIdx.x; i < 8192; i += 512) w2s[i] = e2w[i];
    for (int i = threadIdx.x; i < 1024; i += 512) b2s[i] = e2b[i];
    __syncthreads();

    int ln = threadIdx.x >> 5;
    int o  = threadIdx.x & 31;
    int base = blockIdx.x * nodes_per_block;
    int endn = min(base + nodes_per_block, N);
    for (int n0 = base; n0 < endn; n0 += NPB) {
        int n = n0 + ln;
        bool valid = (n < endn);
        float hv = 0.f;
        if (valid) {
            float acc = proj_b[o];
            #pragma unroll
            for (int i = 0; i < 4; ++i) acc += x[n * 4 + i] * proj_w[i * H + o];
            hv = fmaxf(acc, 0.f);
            h[n * H + o] = hv;
            agg[n * H + o] = 0.f;
        }
        hs[ln][o] = hv;
        __syncthreads();
        if (valid) {
            float acc[8] = {0.f,0.f,0.f,0.f,0.f,0.f,0.f,0.f};
            float accb = 0.f;
            for (int i = 0; i < H; ++i) {
                float hvi = hs[ln][i];
                #pragma unroll
                for (int k = 0; k < 8; ++k) acc[k] += hvi * w2s[k * 1024 + i * H + o];
                accb += hvi * b2s[i * H + o];
            }
            float* Gp = G + (size_t)n * 288;
            #pragma unroll
            for (int k = 0; k < 8; ++k) Gp[k * H + o] = acc[k];
            Gp[8 * H + o] = accb;
        }
        __syncthreads();
    }
}

// ---------------- edges: m[e,o] = Σ_k t_k G[src,k,o] + G[src,8,o]; atomic agg[dst] ----------------
__global__ __launch_bounds__(256) void k_edge(
    const int* __restrict__ ei, const float* __restrict__ ea,
    const float* __restrict__ e1w, const float* __restrict__ e1b,
    const float* __restrict__ G, float* __restrict__ agg, int E)
{
    int tid = blockIdx.x * 256 + threadIdx.x;
    int e = tid >> 5;
    int o = tid & 31;
    if (e >= E) return;
    int src = ei[e];
    int dst = ei[E + e];
    float a = ea[e];
    const float* Gp = G + (size_t)src * 288;
    float m = Gp[8 * H + o];
    #pragma unroll
    for (int k = 0; k < 8; ++k) {
        float t = fmaxf(a * e1w[k] + e1b[k], 0.f);
        m += t * Gp[k * H + o];
    }
    atomicAdd(&agg[dst * H + o], m);
}

// ---------------- node update: GRU(h, agg) -> h; re-zero agg; optionally recompute G ----------------
__global__ __launch_bounds__(512) void k_update(
    float* __restrict__ h, float* __restrict__ agg,
    const float* __restrict__ root_w, const float* __restrict__ conv_b,
    const float* __restrict__ gru_wi, const float* __restrict__ gru_wh,
    const float* __restrict__ gru_bi, const float* __restrict__ gru_bh,
    const float* __restrict__ e2w, const float* __restrict__ e2b,
    float* __restrict__ G, int N, int nodes_per_block, int computeG)
{
    __shared__ float w2s[8 * 1024];
    __shared__ float b2s[1024];
    __shared__ float rws[H * H];
    __shared__ float wiT[H * 96];
    __shared__ float whT[H * 96];
    __shared__ float hs[NPB][H];
    __shared__ float outs[NPB][H];

    for (int i = threadIdx.x; i < 8192; i += 512) w2s[i] = e2w[i];
    for (int i = threadIdx.x; i < 1024; i += 512) b2s[i] = e2b[i];
    for (int i = threadIdx.x; i < 1024; i += 512) rws[i] = root_w[i];
    for (int i = threadIdx.x; i < 3072; i += 512) {
        int j = i / H, ii = i % H;         // j in [0,96)
        wiT[ii * 96 + j] = gru_wi[j * H + ii];
        whT[ii * 96 + j] = gru_wh[j * H + ii];
    }
    __syncthreads();

    int ln = threadIdx.x >> 5;
    int o  = threadIdx.x & 31;
    int base = blockIdx.x * nodes_per_block;
    int endn = min(base + nodes_per_block, N);
    for (int n0 = base; n0 < endn; n0 += NPB) {
        int n = n0 + ln;
        bool valid = (n < endn);
        float hv = valid ? h[n * H + o] : 0.f;
        hs[ln][o] = hv;
        __syncthreads();
        float outv = 0.f;
        if (valid) {
            float tmp = conv_b[o] + agg[n * H + o];
            agg[n * H + o] = 0.f;          // re-zero for next iteration's atomics
            for (int i = 0; i < H; ++i) tmp += hs[ln][i] * rws[i * H + o];
            outv = fmaxf(tmp, 0.f);
        }
        outs[ln][o] = outv;
        __syncthreads();
        float hnew = 0.f;
        if (valid) {
            float gi0 = gru_bi[o],         gh0 = gru_bh[o];
            float gi1 = gru_bi[H + o],     gh1 = gru_bh[H + o];
            float gi2 = gru_bi[2 * H + o], gh2 = gru_bh[2 * H + o];
            for (int i = 0; i < H; ++i) {
                float ov = outs[ln][i], hvi = hs[ln][i];
                gi0 += ov * wiT[i * 96 + o];
                gi1 += ov * wiT[i * 96 + H + o];
                gi2 += ov * wiT[i * 96 + 2 * H + o];
                gh0 += hvi * whT[i * 96 + o];
                gh1 += hvi * whT[i * 96 + H + o];
                gh2 += hvi * whT[i * 96 + 2 * H + o];
            }
            float r = 1.f / (1.f + expf(-(gi0 + gh0)));
            float z = 1.f / (1.f + expf(-(gi1 + gh1)));
            float nn = tanhf(gi2 + r * gh2);
            hnew = (1.f - z) * nn + z * hv;
            h[n * H + o] = hnew;
        }
        __syncthreads();
        hs[ln][o] = hnew;
        __syncthreads();
        if (computeG && valid) {
            float acc[8] = {0.f,0.f,0.f,0.f,0.f,0.f,0.f,0.f};
            float accb = 0.f;
            for (int i = 0; i < H; ++i) {
                float hvi = hs[ln][i];
                #pragma unroll
                for (int k = 0; k < 8; ++k) acc[k] += hvi * w2s[k * 1024 + i * H + o];
                accb += hvi * b2s[i * H + o];
            }
            float* Gp = G + (size_t)n * 288;
            #pragma unroll
            for (int k = 0; k < 8; ++k) Gp[k * H + o] = acc[k];
            Gp[8 * H + o] = accb;
        }
        __syncthreads();
    }
}

// ---------------- q vector from LSTM biases (identical for all b); zero accumulators ----------------
__global__ __launch_bounds__(64) void k_q(
    const float* __restrict__ lstm_bi, const float* __restrict__ lstm_bh,
    float* __restrict__ qvec, unsigned int* __restrict__ segmax,
    float* __restrict__ ssum, float* __restrict__ vsum)
{
    int tid = threadIdx.x;
    if (tid < H) {
        float g0 = lstm_bi[tid] + lstm_bh[tid];
        float g2 = lstm_bi[2 * H + tid] + lstm_bh[2 * H + tid];
        float g3 = lstm_bi[3 * H + tid] + lstm_bh[3 * H + tid];
        float ig = 1.f / (1.f + expf(-g0));
        float gg = tanhf(g2);
        float og = 1.f / (1.f + expf(-g3));
        qvec[tid] = og * tanhf(ig * gg);   // cL starts at 0, f_g*0 drops out
    }
    for (int i = tid; i < BSEG; i += 64) { segmax[i] = 0u; ssum[i] = 0.f; }
    for (int i = tid; i < BSEG * H; i += 64) vsum[i] = 0.f;
}

__device__ __forceinline__ unsigned int fenc(float f) {
    int i = __float_as_int(f);
    return (i >= 0) ? ((unsigned int)i | 0x80000000u) : ~(unsigned int)i;
}
__device__ __forceinline__ float fdec(unsigned int u) {
    int i = (u & 0x80000000u) ? (int)(u & 0x7FFFFFFFu) : (int)(~u);
    return __int_as_float(i);
}

// ---------------- readout pass1: e[n] = h[n]·q, segment max ----------------
__global__ __launch_bounds__(256) void k_pass1(
    const float* __restrict__ h, const int* __restrict__ batch,
    const float* __restrict__ qvec, float* __restrict__ ebuf,
    unsigned int* __restrict__ segmax, int N)
{
    int b = blockIdx.x / CHUNKS;
    int c = blockIdx.x % CHUNKS;
    int lo = 0, hi = N;
    while (lo < hi) { int mid = (lo + hi) >> 1; if (batch[mid] < b) lo = mid + 1; else hi = mid; }
    int s = lo;
    lo = 0; hi = N;
    while (lo < hi) { int mid = (lo + hi) >> 1; if (batch[mid] < b + 1) lo = mid + 1; else hi = mid; }
    int e = lo;
    int len = e - s;
    int per = (len + CHUNKS - 1) / CHUNKS;
    int n0 = s + c * per;
    int n1 = min(n0 + per, e);

    int tid = threadIdx.x;
    int ln = tid >> 5, o = tid & 31;
    float qv = qvec[o];
    float mloc = -INFINITY;
    for (int n = n0 + ln; n < n1; n += 8) {
        float v = h[n * H + o] * qv;
        #pragma unroll
        for (int m = 16; m >= 1; m >>= 1) v += __shfl_xor(v, m);
        if (o == 0) ebuf[n] = v;
        mloc = fmaxf(mloc, v);
    }
    __shared__ float red[256];
    red[tid] = mloc;
    __syncthreads();
    for (int st = 128; st >= 1; st >>= 1) {
        if (tid < st) red[tid] = fmaxf(red[tid], red[tid + st]);
        __syncthreads();
    }
    if (tid == 0 && n0 < n1) atomicMax(&segmax[b], fenc(red[0]));
}

// ---------------- readout pass2: a = exp(e - emax); vsum += a*h; ssum += a ----------------
__global__ __launch_bounds__(256) void k_pass2(
    const float* __restrict__ h, const int* __restrict__ batch,
    const float* __restrict__ ebuf, const unsigned int* __restrict__ segmax,
    float* __restrict__ ssum, float* __restrict__ vsum, int N)
{
    int b = blockIdx.x / CHUNKS;
    int c = blockIdx.x % CHUNKS;
    int lo = 0, hi = N;
    while (lo < hi) { int mid = (lo + hi) >> 1; if (batch[mid] < b) lo = mid + 1; else hi = mid; }
    int s = lo;
    lo = 0; hi = N;
    while (lo < hi) { int mid = (lo + hi) >> 1; if (batch[mid] < b + 1) lo = mid + 1; else hi = mid; }
    int e = lo;
    int len = e - s;
    int per = (len + CHUNKS - 1) / CHUNKS;
    int n0 = s + c * per;
    int n1 = min(n0 + per, e);

    int tid = threadIdx.x;
    int ln = tid >> 5, o = tid & 31;
    float emax = fdec(segmax[b]);
    float vacc = 0.f, sacc = 0.f;
    for (int n = n0 + ln; n < n1; n += 8) {
        float a = expf(ebuf[n] - emax);
        vacc += a * h[n * H + o];
        if (o == 0) sacc += a;
    }
    __shared__ float vsh[8][H];
    __shared__ float ssh[8];
    vsh[ln][o] = vacc;
    if (o == 0) ssh[ln] = sacc;
    __syncthreads();
    if (tid < H) {
        float v = 0.f;
        #pragma unroll
        for (int g = 0; g < 8; ++g) v += vsh[g][tid];
        if (v != 0.f || true) atomicAdd(&vsum[b * H + tid], v);
    } else if (tid == H) {
        float stot = 0.f;
        #pragma unroll
        for (int g = 0; g < 8; ++g) stot += ssh[g];
        atomicAdd(&ssum[b], stot);
    }
}

// ---------------- final MLP on (16, 64) ----------------
__global__ __launch_bounds__(512) void k_mlp(
    const float* __restrict__ qvec, const float* __restrict__ ssum, const float* __restrict__ vsum,
    const float* __restrict__ f1w, const float* __restrict__ f1b,
    const float* __restrict__ f2w, const float* __restrict__ f2b,
    const float* __restrict__ f3w, const float* __restrict__ f3b,
    float* __restrict__ out)
{
    __shared__ float qsm[BSEG][2 * H];
    __shared__ float o1[BSEG][H];
    __shared__ float o2[BSEG][H];
    int tid = threadIdx.x;
    int b = tid >> 5, j = tid & 31;
    float st = ssum[b];
    qsm[b][j] = qvec[j];
    qsm[b][H + j] = (st > 0.f) ? vsum[b * H + j] / st : 0.f;
    __syncthreads();
    float acc = f1b[j];
    for (int i = 0; i < 2 * H; ++i) acc += qsm[b][i] * f1w[i * H + j];
    o1[b][j] = fmaxf(acc, 0.f);
    __syncthreads();
    acc = f2b[j];
    for (int i = 0; i < H; ++i) acc += o1[b][i] * f2w[i * H + j];
    o2[b][j] = fmaxf(acc, 0.f);
    __syncthreads();
    float v = o2[b][j] * f3w[j];
    #pragma unroll
    for (int m = 16; m >= 1; m >>= 1) v += __shfl_xor(v, m);
    if (j == 0) out[b] = v + f3b[0];
}

extern "C" void kernel_launch(void* const* d_in, const int* in_sizes, int n_in,
                              void* d_out, int out_size, void* d_ws, size_t ws_size,
                              hipStream_t stream)
{
    const float* x      = (const float*)d_in[0];
    const int*   ei     = (const int*)d_in[1];
    const float* ea     = (const float*)d_in[2];
    const int*   batch  = (const int*)d_in[3];
    const float* proj_w = (const float*)d_in[4];
    const float* proj_b = (const float*)d_in[5];
    const float* e1w    = (const float*)d_in[6];
    const float* e1b    = (const float*)d_in[7];
    const float* e2w    = (const float*)d_in[8];
    const float* e2b    = (const float*)d_in[9];
    const float* root_w = (const float*)d_in[10];
    const float* conv_b = (const float*)d_in[11];
    const float* gru_wi = (const float*)d_in[12];
    const float* gru_wh = (const float*)d_in[13];
    const float* gru_bi = (const float*)d_in[14];
    const float* gru_bh = (const float*)d_in[15];
    const float* lstm_bi = (const float*)d_in[18];
    const float* lstm_bh = (const float*)d_in[19];
    const float* f1w    = (const float*)d_in[20];
    const float* f1b    = (const float*)d_in[21];
    const float* f2w    = (const float*)d_in[22];
    const float* f2b    = (const float*)d_in[23];
    const float* f3w    = (const float*)d_in[24];
    const float* f3b    = (const float*)d_in[25];

    const int N = in_sizes[0] / 4;
    const int E = in_sizes[2];

    float* ws   = (float*)d_ws;
    float* h    = ws;                       // N*H
    float* G    = h + (size_t)N * H;        // N*288
    float* agg  = G + (size_t)N * 288;      // N*H
    float* ebuf = agg + (size_t)N * H;      // N
    float* qvec = ebuf + N;                 // H
    unsigned int* segmax = (unsigned int*)(qvec + H);  // BSEG
    float* ssum = (float*)(segmax + BSEG);  // BSEG
    float* vsum = ssum + BSEG;              // BSEG*H

    const int NPBK = 80;                    // nodes per block
    const int nblocks = (N + NPBK - 1) / NPBK;
    const int eblocks = (E * 32 + 255) / 256;

    k_init<<<nblocks, 512, 0, stream>>>(x, proj_w, proj_b, e2w, e2b, h, G, agg, N, NPBK);
    k_q<<<1, 64, 0, stream>>>(lstm_bi, lstm_bh, qvec, segmax, ssum, vsum);
    for (int it = 0; it < 3; ++it) {
        k_edge<<<eblocks, 256, 0, stream>>>(ei, ea, e1w, e1b, G, agg, E);
        k_update<<<nblocks, 512, 0, stream>>>(h, agg, root_w, conv_b, gru_wi, gru_wh,
                                              gru_bi, gru_bh, e2w, e2b, G, N, NPBK, it < 2 ? 1 : 0);
    }
    k_pass1<<<BSEG * CHUNKS, 256, 0, stream>>>(h, batch, qvec, ebuf, segmax, N);
    k_pass2<<<BSEG * CHUNKS, 256, 0, stream>>>(h, batch, ebuf, segmax, ssum, vsum, N);
    k_mlp<<<1, 512, 0, stream>>>(qvec, ssum, vsum, f1w, f1b, f2w, f2b, f3w, f3b, (float*)d_out);
}

// Round 3
// 273.351 us; speedup vs baseline: 1.2978x; 1.0233x over previous
//
#include <hip/hip_runtime.h>
#include <math.h>

#define H 32
#define BSEG 16
#define CHUNKS 32
#define NT 32          // nodes per tile

__device__ __forceinline__ float sigmoidf_(float x){ return 1.f/(1.f+expf(-x)); }

// ---------------- prep: permuted weight layouts + qvec + zero accumulators ----------------
// W1 [32][128]: cols 0..31 = root_w[i][c]; cols 32+j = gru_wh[j][i]
// W2 [32][96] : W2[i][j] = gru_wi[j][i]
// W3 [32][288]: W3[i][k*32+o] = e2w[k*1024+i*32+o] (k<8), e2b[i*32+o] (k==8)
__global__ __launch_bounds__(512) void k_prep(
    const float* __restrict__ root_w, const float* __restrict__ gru_wi, const float* __restrict__ gru_wh,
    const float* __restrict__ e2w, const float* __restrict__ e2b,
    const float* __restrict__ lstm_bi, const float* __restrict__ lstm_bh,
    float* __restrict__ W1, float* __restrict__ W2, float* __restrict__ W3,
    float* __restrict__ qvec, unsigned int* __restrict__ segmax,
    float* __restrict__ ssum, float* __restrict__ vsum)
{
    int t = threadIdx.x;
    for (int idx = t; idx < 32*128; idx += 512) {
        int i = idx >> 7, c = idx & 127;
        W1[idx] = (c < 32) ? root_w[i*32 + c] : gru_wh[(c-32)*32 + i];
    }
    for (int idx = t; idx < 32*96; idx += 512) {
        int i = idx / 96, j = idx % 96;
        W2[idx] = gru_wi[j*32 + i];
    }
    for (int idx = t; idx < 32*288; idx += 512) {
        int i = idx / 288, c = idx % 288;
        int k = c >> 5, o = c & 31;
        W3[idx] = (k < 8) ? e2w[k*1024 + i*32 + o] : e2b[i*32 + o];
    }
    if (t < H) {
        float g0 = lstm_bi[t] + lstm_bh[t];
        float g2 = lstm_bi[2*H + t] + lstm_bh[2*H + t];
        float g3 = lstm_bi[3*H + t] + lstm_bh[3*H + t];
        float ig = sigmoidf_(g0);
        float gg = tanhf(g2);
        float og = sigmoidf_(g3);
        qvec[t] = og * tanhf(ig * gg);
    }
    for (int i = t; i < BSEG; i += 512) { segmax[i] = 0u; ssum[i] = 0.f; }
    for (int i = t; i < BSEG*H; i += 512) vsum[i] = 0.f;
}

// ---------------- register-tiled GEMM: 32 nodes x 32 outputs per wave, K=32 ----------------
// lane = og*8+ng: ng owns nodes ng*4..+3, og owns cols cbase+og*4..+3
__device__ __forceinline__ void gemm32(const float A[32][36], int ng, int og,
                                       const float* __restrict__ W, int ncols, int cbase,
                                       float acc[4][4])
{
    #pragma unroll
    for (int i = 0; i < 32; ++i) {
        const float4 av = *(const float4*)&A[i][ng*4];
        const float4 wv = *(const float4*)(W + i*ncols + cbase + og*4);
        float a_[4] = {av.x, av.y, av.z, av.w};
        float w_[4] = {wv.x, wv.y, wv.z, wv.w};
        #pragma unroll
        for (int a = 0; a < 4; ++a)
            #pragma unroll
            for (int b = 0; b < 4; ++b)
                acc[a][b] = fmaf(a_[a], w_[b], acc[a][b]);
    }
}

// ---------------- pre: h = relu(x@proj_w+proj_b); G = h@W3; agg = 0 ----------------
__global__ __launch_bounds__(256) void k_pre(
    const float* __restrict__ x, const float* __restrict__ proj_w, const float* __restrict__ proj_b,
    const float* __restrict__ W3,
    float* __restrict__ h, float* __restrict__ G, float* __restrict__ agg, int N)
{
    __shared__ float hsT[32][36];
    int tid = threadIdx.x;
    int base = blockIdx.x * NT;
    int n_ = tid & 31, fq = tid >> 5;
    int n = base + n_;
    {
        float r_[4];
        if (n < N) {
            float4 xv = *(const float4*)&x[n*4];
            #pragma unroll
            for (int j = 0; j < 4; ++j) {
                int f = fq*4 + j;
                float accv = proj_b[f];
                accv = fmaf(xv.x, proj_w[0*32+f], accv);
                accv = fmaf(xv.y, proj_w[1*32+f], accv);
                accv = fmaf(xv.z, proj_w[2*32+f], accv);
                accv = fmaf(xv.w, proj_w[3*32+f], accv);
                r_[j] = fmaxf(accv, 0.f);
            }
            *(float4*)&h[n*32 + fq*4]   = make_float4(r_[0], r_[1], r_[2], r_[3]);
            *(float4*)&agg[n*32 + fq*4] = make_float4(0,0,0,0);
        } else { r_[0]=r_[1]=r_[2]=r_[3]=0.f; }
        #pragma unroll
        for (int j = 0; j < 4; ++j) hsT[fq*4+j][n_] = r_[j];
    }
    __syncthreads();
    int w = tid >> 6, lane = tid & 63, ng = lane & 7, og = lane >> 3;
    for (int c = w; c < 9; c += 4) {
        float acc[4][4] = {};
        gemm32(hsT, ng, og, W3, 288, c*32, acc);
        #pragma unroll
        for (int a = 0; a < 4; ++a) {
            int nn = base + ng*4 + a;
            if (nn < N)
                *(float4*)&G[(size_t)nn*288 + c*32 + og*4] =
                    make_float4(acc[a][0], acc[a][1], acc[a][2], acc[a][3]);
        }
    }
}

// ---------------- fused node update: out/gh -> gi -> GRU -> (G recompute) ----------------
__global__ __launch_bounds__(256) void k_fused(
    float* __restrict__ h, float* __restrict__ agg,
    const float* __restrict__ conv_b,
    const float* __restrict__ gru_bi, const float* __restrict__ gru_bh,
    const float* __restrict__ W1, const float* __restrict__ W2, const float* __restrict__ W3,
    float* __restrict__ G, int N, int computeG)
{
    __shared__ float hsT[32][36];       // feature-major: hsT[f][n]
    __shared__ float outT[32][36];
    __shared__ float ghL[3][32][36];    // [chunk][feature][node]
    __shared__ float giL[3][32][36];
    int tid = threadIdx.x;
    int base = blockIdx.x * NT;
    int n_ = tid & 31, fq = tid >> 5;
    int n = base + n_;
    {
        float4 hv = (n < N) ? *(const float4*)&h[n*32 + fq*4] : make_float4(0,0,0,0);
        hsT[fq*4+0][n_] = hv.x; hsT[fq*4+1][n_] = hv.y;
        hsT[fq*4+2][n_] = hv.z; hsT[fq*4+3][n_] = hv.w;
    }
    __syncthreads();
    int w = tid >> 6, lane = tid & 63, ng = lane & 7, og = lane >> 3;

    // GEMM1: chunk w of [out(root_w) | gh0 | gh1 | gh2]
    {
        float acc[4][4] = {};
        gemm32(hsT, ng, og, W1, 128, w*32, acc);
        if (w == 0) {
            float4 cbv = *(const float4*)&conv_b[og*4];
            float cb_[4] = {cbv.x, cbv.y, cbv.z, cbv.w};
            #pragma unroll
            for (int a = 0; a < 4; ++a) {
                int nn = base + ng*4 + a;
                float ag_[4] = {0,0,0,0};
                if (nn < N) {
                    float4 agv = *(const float4*)&agg[nn*32 + og*4];
                    ag_[0]=agv.x; ag_[1]=agv.y; ag_[2]=agv.z; ag_[3]=agv.w;
                }
                #pragma unroll
                for (int b = 0; b < 4; ++b)
                    outT[og*4+b][ng*4+a] = fmaxf(acc[a][b] + ag_[b] + cb_[b], 0.f);
            }
        } else {
            #pragma unroll
            for (int a = 0; a < 4; ++a)
                #pragma unroll
                for (int b = 0; b < 4; ++b)
                    ghL[w-1][og*4+b][ng*4+a] = acc[a][b];
        }
    }
    __syncthreads();

    // GEMM2: gi chunks on waves 0..2
    if (w < 3) {
        float acc[4][4] = {};
        gemm32(outT, ng, og, W2, 96, w*32, acc);
        #pragma unroll
        for (int a = 0; a < 4; ++a)
            #pragma unroll
            for (int b = 0; b < 4; ++b)
                giL[w][og*4+b][ng*4+a] = acc[a][b];
    }
    __syncthreads();

    // elementwise GRU: thread (n_, fq) handles features fq*4..+3 of node n_
    {
        float hn_[4];
        #pragma unroll
        for (int j = 0; j < 4; ++j) {
            int f = fq*4 + j;
            float gi0 = giL[0][f][n_] + gru_bi[f];
            float gh0 = ghL[0][f][n_] + gru_bh[f];
            float gi1 = giL[1][f][n_] + gru_bi[32+f];
            float gh1 = ghL[1][f][n_] + gru_bh[32+f];
            float gi2 = giL[2][f][n_] + gru_bi[64+f];
            float gh2 = ghL[2][f][n_] + gru_bh[64+f];
            float r  = sigmoidf_(gi0 + gh0);
            float z  = sigmoidf_(gi1 + gh1);
            float nc = tanhf(gi2 + r*gh2);
            float hold = hsT[f][n_];
            hn_[j] = (1.f - z)*nc + z*hold;
        }
        if (n < N) {
            *(float4*)&h[n*32 + fq*4]   = make_float4(hn_[0], hn_[1], hn_[2], hn_[3]);
            *(float4*)&agg[n*32 + fq*4] = make_float4(0,0,0,0);   // re-zero for next k_edge
        }
        #pragma unroll
        for (int j = 0; j < 4; ++j) hsT[fq*4+j][n_] = hn_[j];
    }
    __syncthreads();

    if (computeG) {
        for (int c = w; c < 9; c += 4) {
            float acc[4][4] = {};
            gemm32(hsT, ng, og, W3, 288, c*32, acc);
            #pragma unroll
            for (int a = 0; a < 4; ++a) {
                int nn = base + ng*4 + a;
                if (nn < N)
                    *(float4*)&G[(size_t)nn*288 + c*32 + og*4] =
                        make_float4(acc[a][0], acc[a][1], acc[a][2], acc[a][3]);
            }
        }
    }
}

// ---------------- edges: m[e,o] = Σ_k t_k G[src,k,o] + G[src,8,o]; atomic agg[dst] ----------------
__global__ __launch_bounds__(256) void k_edge(
    const int* __restrict__ ei, const float* __restrict__ ea,
    const float* __restrict__ e1w, const float* __restrict__ e1b,
    const float* __restrict__ G, float* __restrict__ agg, int E)
{
    int tid = blockIdx.x * 256 + threadIdx.x;
    int e = tid >> 5;
    int o = tid & 31;
    if (e >= E) return;
    int src = ei[e];
    int dst = ei[E + e];
    float a = ea[e];
    const float* Gp = G + (size_t)src * 288;
    float m = Gp[8 * H + o];
    #pragma unroll
    for (int k = 0; k < 8; ++k) {
        float t = fmaxf(a * e1w[k] + e1b[k], 0.f);
        m += t * Gp[k * H + o];
    }
    atomicAdd(&agg[dst * H + o], m);
}

__device__ __forceinline__ unsigned int fenc(float f) {
    int i = __float_as_int(f);
    return (i >= 0) ? ((unsigned int)i | 0x80000000u) : ~(unsigned int)i;
}
__device__ __forceinline__ float fdec(unsigned int u) {
    int i = (u & 0x80000000u) ? (int)(u & 0x7FFFFFFFu) : (int)(~u);
    return __int_as_float(i);
}

// ---------------- readout pass1: e[n] = h[n]·q, segment max ----------------
__global__ __launch_bounds__(256) void k_pass1(
    const float* __restrict__ h, const int* __restrict__ batch,
    const float* __restrict__ qvec, float* __restrict__ ebuf,
    unsigned int* __restrict__ segmax, int N)
{
    int b = blockIdx.x / CHUNKS;
    int c = blockIdx.x % CHUNKS;
    int lo = 0, hi = N;
    while (lo < hi) { int mid = (lo + hi) >> 1; if (batch[mid] < b) lo = mid + 1; else hi = mid; }
    int s = lo;
    lo = 0; hi = N;
    while (lo < hi) { int mid = (lo + hi) >> 1; if (batch[mid] < b + 1) lo = mid + 1; else hi = mid; }
    int e = lo;
    int len = e - s;
    int per = (len + CHUNKS - 1) / CHUNKS;
    int n0 = s + c * per;
    int n1 = min(n0 + per, e);

    int tid = threadIdx.x;
    int ln = tid >> 5, o = tid & 31;
    float qv = qvec[o];
    float mloc = -INFINITY;
    for (int nn = n0 + ln; nn < n1; nn += 8) {
        float v = h[nn * H + o] * qv;
        #pragma unroll
        for (int m = 16; m >= 1; m >>= 1) v += __shfl_xor(v, m);
        if (o == 0) ebuf[nn] = v;
        mloc = fmaxf(mloc, v);
    }
    __shared__ float red[256];
    red[tid] = mloc;
    __syncthreads();
    for (int st = 128; st >= 1; st >>= 1) {
        if (tid < st) red[tid] = fmaxf(red[tid], red[tid + st]);
        __syncthreads();
    }
    if (tid == 0 && n0 < n1) atomicMax(&segmax[b], fenc(red[0]));
}

// ---------------- readout pass2: a = exp(e - emax); vsum += a*h; ssum += a ----------------
__global__ __launch_bounds__(256) void k_pass2(
    const float* __restrict__ h, const int* __restrict__ batch,
    const float* __restrict__ ebuf, const unsigned int* __restrict__ segmax,
    float* __restrict__ ssum, float* __restrict__ vsum, int N)
{
    int b = blockIdx.x / CHUNKS;
    int c = blockIdx.x % CHUNKS;
    int lo = 0, hi = N;
    while (lo < hi) { int mid = (lo + hi) >> 1; if (batch[mid] < b) lo = mid + 1; else hi = mid; }
    int s = lo;
    lo = 0; hi = N;
    while (lo < hi) { int mid = (lo + hi) >> 1; if (batch[mid] < b + 1) lo = mid + 1; else hi = mid; }
    int e = lo;
    int len = e - s;
    int per = (len + CHUNKS - 1) / CHUNKS;
    int n0 = s + c * per;
    int n1 = min(n0 + per, e);

    int tid = threadIdx.x;
    int ln = tid >> 5, o = tid & 31;
    float emax = fdec(segmax[b]);
    float vacc = 0.f, sacc = 0.f;
    for (int nn = n0 + ln; nn < n1; nn += 8) {
        float a = expf(ebuf[nn] - emax);
        vacc += a * h[nn * H + o];
        if (o == 0) sacc += a;
    }
    __shared__ float vsh[8][H];
    __shared__ float ssh[8];
    vsh[ln][o] = vacc;
    if (o == 0) ssh[ln] = sacc;
    __syncthreads();
    if (tid < H) {
        float v = 0.f;
        #pragma unroll
        for (int g = 0; g < 8; ++g) v += vsh[g][tid];
        atomicAdd(&vsum[b * H + tid], v);
    } else if (tid == H) {
        float stot = 0.f;
        #pragma unroll
        for (int g = 0; g < 8; ++g) stot += ssh[g];
        atomicAdd(&ssum[b], stot);
    }
}

// ---------------- final MLP on (16, 64) ----------------
__global__ __launch_bounds__(512) void k_mlp(
    const float* __restrict__ qvec, const float* __restrict__ ssum, const float* __restrict__ vsum,
    const float* __restrict__ f1w, const float* __restrict__ f1b,
    const float* __restrict__ f2w, const float* __restrict__ f2b,
    const float* __restrict__ f3w, const float* __restrict__ f3b,
    float* __restrict__ out)
{
    __shared__ float qsm[BSEG][2 * H];
    __shared__ float o1[BSEG][H];
    __shared__ float o2[BSEG][H];
    int tid = threadIdx.x;
    int b = tid >> 5, j = tid & 31;
    float st = ssum[b];
    qsm[b][j] = qvec[j];
    qsm[b][H + j] = (st > 0.f) ? vsum[b * H + j] / st : 0.f;
    __syncthreads();
    float acc = f1b[j];
    for (int i = 0; i < 2 * H; ++i) acc += qsm[b][i] * f1w[i * H + j];
    o1[b][j] = fmaxf(acc, 0.f);
    __syncthreads();
    acc = f2b[j];
    for (int i = 0; i < H; ++i) acc += o1[b][i] * f2w[i * H + j];
    o2[b][j] = fmaxf(acc, 0.f);
    __syncthreads();
    float v = o2[b][j] * f3w[j];
    #pragma unroll
    for (int m = 16; m >= 1; m >>= 1) v += __shfl_xor(v, m);
    if (j == 0) out[b] = v + f3b[0];
}

extern "C" void kernel_launch(void* const* d_in, const int* in_sizes, int n_in,
                              void* d_out, int out_size, void* d_ws, size_t ws_size,
                              hipStream_t stream)
{
    const float* x      = (const float*)d_in[0];
    const int*   ei     = (const int*)d_in[1];
    const float* ea     = (const float*)d_in[2];
    const int*   batch  = (const int*)d_in[3];
    const float* proj_w = (const float*)d_in[4];
    const float* proj_b = (const float*)d_in[5];
    const float* e1w    = (const float*)d_in[6];
    const float* e1b    = (const float*)d_in[7];
    const float* e2w    = (const float*)d_in[8];
    const float* e2b    = (const float*)d_in[9];
    const float* root_w = (const float*)d_in[10];
    const float* conv_b = (const float*)d_in[11];
    const float* gru_wi = (const float*)d_in[12];
    const float* gru_wh = (const float*)d_in[13];
    const float* gru_bi = (const float*)d_in[14];
    const float* gru_bh = (const float*)d_in[15];
    const float* lstm_bi = (const float*)d_in[18];
    const float* lstm_bh = (const float*)d_in[19];
    const float* f1w    = (const float*)d_in[20];
    const float* f1b    = (const float*)d_in[21];
    const float* f2w    = (const float*)d_in[22];
    const float* f2b    = (const float*)d_in[23];
    const float* f3w    = (const float*)d_in[24];
    const float* f3b    = (const float*)d_in[25];

    const int N = in_sizes[0] / 4;
    const int E = in_sizes[2];

    float* ws   = (float*)d_ws;
    float* h    = ws;                       // N*32
    float* G    = h + (size_t)N * H;        // N*288
    float* agg  = G + (size_t)N * 288;      // N*32
    float* ebuf = agg + (size_t)N * H;      // N
    float* qvec = ebuf + N;                 // H
    unsigned int* segmax = (unsigned int*)(qvec + H);  // BSEG
    float* ssum = (float*)(segmax + BSEG);  // BSEG
    float* vsum = ssum + BSEG;              // BSEG*H
    float* W1   = vsum + BSEG * H;          // 32*128
    float* W2   = W1 + 32 * 128;            // 32*96
    float* W3   = W2 + 32 * 96;             // 32*288

    const int nb = (N + NT - 1) / NT;
    const int eblocks = (E * 32 + 255) / 256;

    k_prep<<<1, 512, 0, stream>>>(root_w, gru_wi, gru_wh, e2w, e2b, lstm_bi, lstm_bh,
                                  W1, W2, W3, qvec, segmax, ssum, vsum);
    k_pre<<<nb, 256, 0, stream>>>(x, proj_w, proj_b, W3, h, G, agg, N);
    for (int it = 0; it < 3; ++it) {
        k_edge<<<eblocks, 256, 0, stream>>>(ei, ea, e1w, e1b, G, agg, E);
        k_fused<<<nb, 256, 0, stream>>>(h, agg, conv_b, gru_bi, gru_bh,
                                        W1, W2, W3, G, N, it < 2 ? 1 : 0);
    }
    k_pass1<<<BSEG * CHUNKS, 256, 0, stream>>>(h, batch, qvec, ebuf, segmax, N);
    k_pass2<<<BSEG * CHUNKS, 256, 0, stream>>>(h, batch, ebuf, segmax, ssum, vsum, N);
    k_mlp<<<1, 512, 0, stream>>>(qvec, ssum, vsum, f1w, f1b, f2w, f2b, f3w, f3b, (float*)d_out);
}